// Round 13
// baseline (216.416 us; speedup 1.0000x reference)
//
#include <hip/hip_runtime.h>
#include <hip/hip_bf16.h>
#include <stdint.h>

// ---------------------------------------------------------------------------
// Attention layer: x->QKV proj -> RoPE -> causal GQA flash attn -> O proj
// B=2 S=2048 D=2048 H=32 KVH=8 HD=64.
// GEMMs: 256-wide pipelined bf16 MFMA (dbuf LDS + XOR swizzle + stage-ahead)
// with XCD-local column-panel block mapping (T1).
// Attention: 2 GQA heads per wave (K/V fragment loads amortized 2x, softmax
// ILP 2x), swapped QK^T 32x32x16, in-register softmax (trees, defer-max),
// permlane32_swap P-pack, fragment-order K/V, Q-RoPE folded into prologue.
// ---------------------------------------------------------------------------

#define NEG_BIG (-1e9f)
#define SCALE_LOG2 0.18033688011112042f   // (1/sqrt(64)) * log2(e)
#define DEFER_THR 10.0f                   // log2-domain defer-max threshold

typedef __bf16 bf16x8 __attribute__((ext_vector_type(8)));
typedef float f32x4 __attribute__((ext_vector_type(4)));
typedef float f32x16 __attribute__((ext_vector_type(16)));
typedef uint16_t u16x8 __attribute__((ext_vector_type(8)));
typedef uint32_t u32x4 __attribute__((ext_vector_type(4)));

__device__ inline uint16_t f2bf(float x) {
    __hip_bfloat16 h = __float2bfloat16(x);
    return __builtin_bit_cast(uint16_t, h);
}
__device__ inline float bf2f(uint16_t u) {
    uint32_t t = (uint32_t)u << 16;
    return __builtin_bit_cast(float, t);
}

__device__ inline void async_cp16(const void* g, void* l) {
    __builtin_amdgcn_global_load_lds(
        (const __attribute__((address_space(1))) uint32_t*)g,
        (__attribute__((address_space(3))) uint32_t*)l,
        16 /*bytes*/, 0 /*offset*/, 0 /*aux*/);
}

// ------------------------- fp32 -> bf16 cast (4/thread) ---------------------
__global__ void cvt4(const float* __restrict__ in, uint16_t* __restrict__ out, int n4) {
    int i = blockIdx.x * blockDim.x + threadIdx.x;
    if (i >= n4) return;
    const float4 v = ((const float4*)in)[i];
    ushort4 o;
    o.x = f2bf(v.x); o.y = f2bf(v.y); o.z = f2bf(v.z); o.w = f2bf(v.w);
    ((ushort4*)out)[i] = o;
}

// ------------------- build concat W = [wq; wk; wv] in bf16 ------------------
__global__ void build_wqkv(const float* __restrict__ wq, const float* __restrict__ wk,
                           const float* __restrict__ wv, uint16_t* __restrict__ out) {
    int i = blockIdx.x * blockDim.x + threadIdx.x;   // one per 4 elements
    if (i >= (3072 * 2048) / 4) return;
    int e = i * 4;
    int row = e >> 11;           // /2048
    int col = e & 2047;
    const float* src = (row < 2048) ? (wq + (long)row * 2048 + col)
                     : (row < 2560) ? (wk + (long)(row - 2048) * 2048 + col)
                                    : (wv + (long)(row - 2560) * 2048 + col);
    const float4 v = *(const float4*)src;
    ushort4 o;
    o.x = f2bf(v.x); o.y = f2bf(v.y); o.z = f2bf(v.z); o.w = f2bf(v.w);
    ((ushort4*)(out + e))[0] = o;
}

// ----------------------- pipelined 256-wide GEMM (NT) ------------------------
// C[m][n] = sum_k A[m][k]*B[n][k]. BM=256, BN in {192,128}, BK=64.
// 512 threads = 8 waves (2 M x 4 N). Double-buffered LDS; stage-ahead;
// ONE __syncthreads per K-tile; XOR swizzle both-sides; XCD-local col panels.
template <int BN, int OUT_BF16>
__global__ __launch_bounds__(512) void gemm256(const uint16_t* __restrict__ A,
                                               const uint16_t* __restrict__ Bw,
                                               void* __restrict__ Cout,
                                               int M, int N, int K) {
    constexpr int WN = BN / 4;        // per-wave cols
    constexpr int NF = WN / 16;       // B fragments per wave
    constexpr int BROUNDS = BN / 64;  // staging rounds for B

    __shared__ __align__(16) uint16_t As[2][256 * 64];
    __shared__ __align__(16) uint16_t Bs[2][BN * 64];

    const int n0 = blockIdx.x;                       // 0..255
    const int colt = 2 * (n0 & 7) + ((n0 >> 3) >> 4);
    const int rowt = (n0 >> 3) & 15;
    const long row0 = (long)rowt * 256;
    const long col0 = (long)colt * BN;

    const int tid = threadIdx.x;
    const int l = tid & 63;
    const int w = tid >> 6;
    const int wmi = w >> 2;           // 0..1
    const int wni = w & 3;            // 0..3
    const int c = l & 15, g = l >> 4;

    f32x4 acc[8][NF] = {};

    auto STAGE = [&](int buf, int t) {
        const long k0 = (long)t * 64;
#pragma unroll
        for (int rr = 0; rr < 4; ++rr) {
            const int e = rr * 512 + tid;            // 16B-slot index
            const int r = e >> 3;                    // row 0..255
            const int gs = (e & 7) ^ (r & 7);        // inverse-swizzled global slot
            async_cp16(A + (row0 + r) * (long)K + k0 + gs * 8, &As[buf][e * 8]);
        }
#pragma unroll
        for (int rr = 0; rr < BROUNDS; ++rr) {
            const int e = rr * 512 + tid;
            const int r = e >> 3;
            const int gs = (e & 7) ^ (r & 7);
            async_cp16(Bw + (col0 + r) * (long)K + k0 + gs * 8, &Bs[buf][e * 8]);
        }
    };

    STAGE(0, 0);
    __syncthreads();                                  // vmcnt(0) drain + barrier

    const int nt = K / 64;
    for (int t = 0; t < nt; ++t) {
        const int cur = t & 1;
        if (t + 1 < nt) STAGE(cur ^ 1, t + 1);        // overlaps this tile's compute

#pragma unroll
        for (int kk = 0; kk < 2; ++kk) {
            bf16x8 bF[NF];
#pragma unroll
            for (int n = 0; n < NF; ++n) {
                const int rb = wni * WN + n * 16 + c;
                const int sp = ((kk * 4 + g) ^ (c & 7));
                bF[n] = *(const bf16x8*)&Bs[cur][rb * 64 + sp * 8];
            }
#pragma unroll
            for (int mh = 0; mh < 2; ++mh) {
                bf16x8 aF[4];
#pragma unroll
                for (int mm = 0; mm < 4; ++mm) {
                    const int ra = wmi * 128 + (mh * 4 + mm) * 16 + c;
                    const int sp = ((kk * 4 + g) ^ (c & 7));
                    aF[mm] = *(const bf16x8*)&As[cur][ra * 64 + sp * 8];
                }
                __builtin_amdgcn_s_setprio(1);
#pragma unroll
                for (int mm = 0; mm < 4; ++mm)
#pragma unroll
                    for (int n = 0; n < NF; ++n)
                        acc[mh * 4 + mm][n] = __builtin_amdgcn_mfma_f32_16x16x32_bf16(
                            aF[mm], bF[n], acc[mh * 4 + mm][n], 0, 0, 0);
                __builtin_amdgcn_s_setprio(0);
            }
        }
        if (t + 1 < nt) __syncthreads();              // next buffer staged; cur reads done
    }

#pragma unroll
    for (int m = 0; m < 8; ++m) {
        const long rg = row0 + wmi * 128 + m * 16 + g * 4;
#pragma unroll
        for (int n = 0; n < NF; ++n) {
            const long cg = col0 + wni * WN + n * 16 + c;
#pragma unroll
            for (int r = 0; r < 4; ++r) {
                float v = acc[m][n][r];
                if (OUT_BF16)
                    ((uint16_t*)Cout)[(rg + r) * (long)N + cg] = f2bf(v);
                else
                    ((float*)Cout)[(rg + r) * (long)N + cg] = v;
            }
        }
    }
}

// ---------- K (fused RoPE) + V^T -> fragment-order pack, one kernel ----------
// Kpk[bk][tile(64)][s(4)][lane(64)][8], Vpk[bk][tile(64)][nd(2)][s2(2)][lane][8]
__global__ void pack_kv(const uint16_t* __restrict__ qkv,
                        const float* __restrict__ cosT,
                        const float* __restrict__ sinT,
                        uint16_t* __restrict__ Kpk,
                        uint16_t* __restrict__ Vpk) {
    const int gw = (blockIdx.x * blockDim.x + threadIdx.x) >> 6;  // 8192 waves
    const int l = threadIdx.x & 63;
    const int lq = l & 31, hi = l >> 5;
    if (gw < 4096) {
        const int wid = gw;
        const int s = wid & 3;
        const int tile = (wid >> 2) & 63;
        const int bk = wid >> 8;
        const int b = bk >> 3, kvh = bk & 7;
        const int key = 32 * tile + lq;
        const uint16_t* src = qkv + (long)(b * 2048 + key) * 3072
                            + 2048 + kvh * 64 + 16 * s + 8 * hi;
        u16x8 v = *(const u16x8*)src;
        const int d2b = 8 * s + 4 * hi;            // first pair index
        u16x8 o;
#pragma unroll
        for (int p = 0; p < 4; ++p) {
            const float cc = cosT[key * 32 + d2b + p];
            const float ss = sinT[key * 32 + d2b + p];
            const float re = bf2f(v[2 * p]);
            const float im = bf2f(v[2 * p + 1]);
            o[2 * p]     = f2bf(re * cc - im * ss);
            o[2 * p + 1] = f2bf(re * ss + im * cc);
        }
        *(u16x8*)(Kpk + (((long)(bk * 64 + tile) * 4 + s) * 64 + l) * 8) = o;
    } else {
        const int wid = gw - 4096;
        const int s2 = wid & 1;
        const int nd = (wid >> 1) & 1;
        const int tile = (wid >> 2) & 63;
        const int bk = wid >> 8;
        const int b = bk >> 3, kvh = bk & 7;
        const int key0 = 32 * tile + 16 * s2 + 8 * hi;
        const uint16_t* src = qkv + (long)(b * 2048 + key0) * 3072
                            + 2560 + kvh * 64 + nd * 32 + lq;
        u16x8 v;
#pragma unroll
        for (int jj = 0; jj < 8; ++jj) v[jj] = src[(long)jj * 3072];
        *(u16x8*)(Vpk + ((((long)(bk * 64 + tile) * 2 + nd) * 2 + s2) * 64 + l) * 8) = v;
    }
}

// ---------- P^T fragment assembly via permlane32_swap (verified R10+) --------
__device__ inline void pack_pf(const float pr[16], bf16x8 pf[2]) {
    uint32_t wds[8];
#pragma unroll
    for (int m = 0; m < 8; ++m)
        wds[m] = (uint32_t)f2bf(pr[2 * m]) | ((uint32_t)f2bf(pr[2 * m + 1]) << 16);
    asm volatile("v_permlane32_swap_b32 %0, %1" : "+v"(wds[0]), "+v"(wds[2]));
    asm volatile("v_permlane32_swap_b32 %0, %1" : "+v"(wds[1]), "+v"(wds[3]));
    asm volatile("v_permlane32_swap_b32 %0, %1" : "+v"(wds[4]), "+v"(wds[6]));
    asm volatile("v_permlane32_swap_b32 %0, %1" : "+v"(wds[5]), "+v"(wds[7]));
    u32x4 pk0 = {wds[0], wds[1], wds[2], wds[3]};
    u32x4 pk1 = {wds[4], wds[5], wds[6], wds[7]};
    pf[0] = __builtin_bit_cast(bf16x8, pk0);
    pf[1] = __builtin_bit_cast(bf16x8, pk1);
}

// ---------------------------- flash attention -------------------------------
// 1024 blocks x 128 threads (2 waves). Block = (rowset j, b, kvh); wave ww
// processes TWO GQA heads h = 4*kvh + 2*ww + {0,1} for rows 32j..32j+31:
// K/V fragment loads amortized over 2 heads, softmax chains independent (ILP
// x2). Swapped QK^T (S^T = mfma(K,Q), Q RoPE+scaled in prologue, log2
// domain); in-register online softmax (tree max/sum, defer-max T13); P^T via
// permlane32_swap; PV: O^T = mfma(V^T, P^T). j mapping: boustrophedon over
// 16-strides -> per-CU j-sums equal (126), LPT order (largest j first).
__global__ __launch_bounds__(128) void attn_fwd(const uint16_t* __restrict__ qkv,
                                                const float* __restrict__ cosT,
                                                const float* __restrict__ sinT,
                                                const uint16_t* __restrict__ Kpk,
                                                const uint16_t* __restrict__ Vpk,
                                                uint16_t* __restrict__ outb) {
    const int bid = blockIdx.x;
    const int p = bid >> 4;                     // 0..63
    const int k4 = p >> 4, a = p & 15;
    const int j = (3 - k4) * 16 + ((k4 & 1) ? a : (15 - a));   // bijective, LPT
    const int gh2 = bid & 15;
    const int b = gh2 >> 3, kvh = gh2 & 7;
    const int tid = threadIdx.x;
    const int l = tid & 63, ww = tid >> 6;
    const int h0 = 4 * kvh + 2 * ww;            // this wave's heads: h0, h0+1
    const int bk = b * 8 + kvh;
    const int lq = l & 31, hi = l >> 5;
    const int q = 32 * j + lq;

    // Q fragments for both heads (RoPE + SCALE_LOG2; cos/sin shared by heads)
    const uint16_t* qrowb = qkv + (long)(b * 2048 + q) * 3072 + 8 * hi;
    bf16x8 qf[2][4];
#pragma unroll
    for (int s = 0; s < 4; ++s) {
        const int d2b = 8 * s + 4 * hi;
        float cc[4], ss[4];
#pragma unroll
        for (int pp = 0; pp < 4; ++pp) {
            cc[pp] = cosT[q * 32 + d2b + pp];
            ss[pp] = sinT[q * 32 + d2b + pp];
        }
#pragma unroll
        for (int hh = 0; hh < 2; ++hh) {
            const u16x8 v = *(const u16x8*)(qrowb + (h0 + hh) * 64 + 16 * s);
            u16x8 o;
#pragma unroll
            for (int pp = 0; pp < 4; ++pp) {
                const float re = bf2f(v[2 * pp]);
                const float im = bf2f(v[2 * pp + 1]);
                o[2 * pp]     = f2bf((re * cc[pp] - im * ss[pp]) * SCALE_LOG2);
                o[2 * pp + 1] = f2bf((re * ss[pp] + im * cc[pp]) * SCALE_LOG2);
            }
            qf[hh][s] = __builtin_bit_cast(bf16x8, o);
        }
    }

    float m_run[2] = {-1e30f, -1e30f};
    float l_run[2] = {0.f, 0.f};
    f32x16 accO[2][2] = {};                      // [head][nd]

    const uint16_t* kbase = Kpk + (long)bk * 64 * 2048 + (long)l * 8;
    const uint16_t* vbase = Vpk + (long)bk * 64 * 2048 + (long)l * 8;
    const int nT = (j + 2) >> 1;                 // 64-key iterations

    for (int t = 0; t < nT; ++t) {
        // ---- K A-fragments (shared by both heads) ----
        bf16x8 kf[2][4];
#pragma unroll
        for (int u = 0; u < 2; ++u)
#pragma unroll
            for (int s = 0; s < 4; ++s)
                kf[u][s] = *(const bf16x8*)(kbase + (long)(2 * t + u) * 2048 + s * 512);

        // ---- S^T = K Q^T for both heads (16 MFMA cluster) ----
        f32x16 st[2][2];
        __builtin_amdgcn_s_setprio(1);
#pragma unroll
        for (int hh = 0; hh < 2; ++hh) {
            f32x16 z0 = {}, z1 = {};
#pragma unroll
            for (int s = 0; s < 4; ++s)
                z0 = __builtin_amdgcn_mfma_f32_32x32x16_bf16(kf[0][s], qf[hh][s], z0, 0, 0, 0);
#pragma unroll
            for (int s = 0; s < 4; ++s)
                z1 = __builtin_amdgcn_mfma_f32_32x32x16_bf16(kf[1][s], qf[hh][s], z1, 0, 0, 0);
            st[hh][0] = z0;
            st[hh][1] = z1;
        }
        __builtin_amdgcn_s_setprio(0);

        // ---- V^T A-fragments (shared; softmax below hides latency) ----
        bf16x8 vf[2][2][2];
#pragma unroll
        for (int u = 0; u < 2; ++u)
#pragma unroll
            for (int nd = 0; nd < 2; ++nd)
#pragma unroll
                for (int s2 = 0; s2 < 2; ++s2)
                    vf[u][nd][s2] = *(const bf16x8*)(vbase + (long)(2 * t + u) * 2048 + nd * 1024 + s2 * 512);

        // ---- causal mask in-place (last iteration; same mask both heads) ----
        if (t == nT - 1) {
            const int tq0 = lq + ((j - 2 * t) << 5) - 4 * hi;
            const int tq1 = tq0 - 32;
#pragma unroll
            for (int r = 0; r < 16; ++r) {
                const int kc = (r & 3) + 8 * (r >> 2);
#pragma unroll
                for (int hh = 0; hh < 2; ++hh) {
                    if (kc > tq0) st[hh][0][r] = NEG_BIG;
                    if (kc > tq1) st[hh][1][r] = NEG_BIG;
                }
            }
        }

        // ---- per-head softmax + P-pack + PV (chains independent -> ILP) ----
#pragma unroll
        for (int hh = 0; hh < 2; ++hh) {
            float mx[16];
#pragma unroll
            for (int r = 0; r < 16; ++r) mx[r] = fmaxf(st[hh][0][r], st[hh][1][r]);
#pragma unroll
            for (int off = 8; off; off >>= 1)
#pragma unroll
                for (int r = 0; r < 8; ++r)
                    if (r < off) mx[r] = fmaxf(mx[r], mx[r + off]);
            const float vm = fmaxf(mx[0], __shfl_xor(mx[0], 32));

            if (!__all(vm - m_run[hh] <= DEFER_THR)) {
                const float mnew = fmaxf(m_run[hh], vm);
                const float alpha = __builtin_amdgcn_exp2f(m_run[hh] - mnew);
                m_run[hh] = mnew;
                l_run[hh] *= alpha;
#pragma unroll
                for (int nd = 0; nd < 2; ++nd)
#pragma unroll
                    for (int r = 0; r < 16; ++r) accO[hh][nd][r] *= alpha;
            }

            float pr0[16], pr1[16], sm[8];
#pragma unroll
            for (int r = 0; r < 16; ++r) pr0[r] = __builtin_amdgcn_exp2f(st[hh][0][r] - m_run[hh]);
#pragma unroll
            for (int r = 0; r < 16; ++r) pr1[r] = __builtin_amdgcn_exp2f(st[hh][1][r] - m_run[hh]);
#pragma unroll
            for (int m = 0; m < 8; ++m)
                sm[m] = (pr0[2 * m] + pr0[2 * m + 1]) + (pr1[2 * m] + pr1[2 * m + 1]);
#pragma unroll
            for (int off = 4; off; off >>= 1)
#pragma unroll
                for (int r = 0; r < 4; ++r)
                    if (r < off) sm[r] += sm[r + off];
            l_run[hh] += sm[0] + __shfl_xor(sm[0], 32);

            bf16x8 pf0[2], pf1[2];
            pack_pf(pr0, pf0);
            pack_pf(pr1, pf1);

            __builtin_amdgcn_s_setprio(1);
#pragma unroll
            for (int nd = 0; nd < 2; ++nd) {
                accO[hh][nd] = __builtin_amdgcn_mfma_f32_32x32x16_bf16(vf[0][nd][0], pf0[0], accO[hh][nd], 0, 0, 0);
                accO[hh][nd] = __builtin_amdgcn_mfma_f32_32x32x16_bf16(vf[0][nd][1], pf0[1], accO[hh][nd], 0, 0, 0);
                accO[hh][nd] = __builtin_amdgcn_mfma_f32_32x32x16_bf16(vf[1][nd][0], pf1[0], accO[hh][nd], 0, 0, 0);
                accO[hh][nd] = __builtin_amdgcn_mfma_f32_32x32x16_bf16(vf[1][nd][1], pf1[1], accO[hh][nd], 0, 0, 0);
            }
            __builtin_amdgcn_s_setprio(0);
        }
    }

    // ---- epilogue: out[b, q, h*64 + d], d = nd*32 + (r&3)+4hi+8(r>>2) ----
#pragma unroll
    for (int hh = 0; hh < 2; ++hh) {
        const float invl = 1.0f / l_run[hh];
        uint16_t* orow = outb + (long)(b * 2048 + q) * 2048 + (h0 + hh) * 64 + 4 * hi;
#pragma unroll
        for (int nd = 0; nd < 2; ++nd)
#pragma unroll
            for (int m = 0; m < 4; ++m) {
                ushort4 o;
                o.x = f2bf(accO[hh][nd][4 * m + 0] * invl);
                o.y = f2bf(accO[hh][nd][4 * m + 1] * invl);
                o.z = f2bf(accO[hh][nd][4 * m + 2] * invl);
                o.w = f2bf(accO[hh][nd][4 * m + 3] * invl);
                *(ushort4*)(orow + nd * 32 + 8 * m) = o;
            }
    }
}

// ---------------------------------------------------------------------------
extern "C" void kernel_launch(void* const* d_in, const int* in_sizes, int n_in,
                              void* d_out, int out_size, void* d_ws, size_t ws_size,
                              hipStream_t stream) {
    const float* x    = (const float*)d_in[0];
    const float* wq   = (const float*)d_in[1];
    const float* wk   = (const float*)d_in[2];
    const float* wv   = (const float*)d_in[3];
    const float* wo   = (const float*)d_in[4];
    const float* fcos = (const float*)d_in[5];
    const float* fsin = (const float*)d_in[6];
    // d_in[7] = mask: causal, computed analytically in attn_fwd.
    float* out = (float*)d_out;

    uint8_t* ws = (uint8_t*)d_ws;
    // layout (bytes), total 52 MiB:
    //   [0,        16 MiB)   x_bf [4096][2048]   -- reused as att_bf
    //   [16 MiB,   28 MiB)   w_bf [3072][2048]   -- after GEMM1:
    //                          Kpk @16MiB (4MiB), Vpk @20MiB (4MiB);
    //                          after attn: wo_bf @16MiB (8MiB)
    //   [28 MiB,   52 MiB)   qkv_bf [4096][3072]
    const size_t MiB = 1048576;
    uint16_t* x_bf   = (uint16_t*)(ws);
    uint16_t* w_bf   = (uint16_t*)(ws + 16 * MiB);
    uint16_t* qkv_bf = (uint16_t*)(ws + 28 * MiB);
    uint16_t* att_bf = x_bf;                        // alias after GEMM1
    uint16_t* Kpk    = (uint16_t*)(ws + 16 * MiB);  // alias after GEMM1
    uint16_t* Vpk    = (uint16_t*)(ws + 20 * MiB);
    uint16_t* wo_bf  = (uint16_t*)(ws + 16 * MiB);  // alias after attn

    // 1) casts
    cvt4<<<(2097152 + 255) / 256, 256, 0, stream>>>(x, x_bf, 2097152);
    build_wqkv<<<(1572864 + 255) / 256, 256, 0, stream>>>(wq, wk, wv, w_bf);

    // 2) QKV projection: [4096][3072] = x_bf @ w_bf^T  (256x192, 256 blocks,
    //    XCD-local column panels)
    gemm256<192, 1><<<256, 512, 0, stream>>>(x_bf, w_bf, qkv_bf, 4096, 3072, 2048);

    // 3) K-RoPE + fragment packs (Q stays raw; attn ropes Q in-register)
    pack_kv<<<2048, 256, 0, stream>>>(qkv_bf, fcos, fsin, Kpk, Vpk);

    // 4) flash attention (2 heads/wave) -> att_bf [4096][2048]
    attn_fwd<<<1024, 128, 0, stream>>>(qkv_bf, fcos, fsin, Kpk, Vpk, att_bf);

    // 5) wo cast (Kpk/Vpk dead now), O projection -> fp32 out (256x128,
    //    256 blocks, XCD-local column panels)
    cvt4<<<(1048576 + 255) / 256, 256, 0, stream>>>(wo, wo_bf, 1048576);
    gemm256<128, 0><<<256, 512, 0, stream>>>(att_bf, wo_bf, out, 4096, 2048, 2048);
}

// Round 14
// 202.763 us; speedup vs baseline: 1.0673x; 1.0673x over previous
//
#include <hip/hip_runtime.h>
#include <hip/hip_bf16.h>
#include <stdint.h>

// ---------------------------------------------------------------------------
// Attention layer: x->QKV proj -> RoPE -> causal GQA flash attn -> O proj
// B=2 S=2048 D=2048 H=32 KVH=8 HD=64.
// GEMMs: 256-wide pipelined bf16 MFMA (dbuf LDS + XOR swizzle + stage-ahead)
// with XCD-local column-panel block mapping (T1).
// Attention: R12-verified structure: 2-wave blocks, swapped QK^T 32x32x16,
// in-register softmax (trees, defer-max), permlane32_swap P-pack,
// fragment-order K/V, Q-RoPE+scale folded into the prologue.
// ---------------------------------------------------------------------------

#define NEG_BIG (-1e9f)
#define SCALE_LOG2 0.18033688011112042f   // (1/sqrt(64)) * log2(e)
#define DEFER_THR 10.0f                   // log2-domain defer-max threshold

typedef __bf16 bf16x8 __attribute__((ext_vector_type(8)));
typedef float f32x4 __attribute__((ext_vector_type(4)));
typedef float f32x16 __attribute__((ext_vector_type(16)));
typedef uint16_t u16x8 __attribute__((ext_vector_type(8)));
typedef uint32_t u32x4 __attribute__((ext_vector_type(4)));

__device__ inline uint16_t f2bf(float x) {
    __hip_bfloat16 h = __float2bfloat16(x);
    return __builtin_bit_cast(uint16_t, h);
}
__device__ inline float bf2f(uint16_t u) {
    uint32_t t = (uint32_t)u << 16;
    return __builtin_bit_cast(float, t);
}

__device__ inline void async_cp16(const void* g, void* l) {
    __builtin_amdgcn_global_load_lds(
        (const __attribute__((address_space(1))) uint32_t*)g,
        (__attribute__((address_space(3))) uint32_t*)l,
        16 /*bytes*/, 0 /*offset*/, 0 /*aux*/);
}

// ------------------------- fp32 -> bf16 cast (4/thread) ---------------------
__global__ void cvt4(const float* __restrict__ in, uint16_t* __restrict__ out, int n4) {
    int i = blockIdx.x * blockDim.x + threadIdx.x;
    if (i >= n4) return;
    const float4 v = ((const float4*)in)[i];
    ushort4 o;
    o.x = f2bf(v.x); o.y = f2bf(v.y); o.z = f2bf(v.z); o.w = f2bf(v.w);
    ((ushort4*)out)[i] = o;
}

// --------- fused prep: x cast + concat W = [wq; wk; wv] cast (1 launch) ------
__global__ void prep(const float* __restrict__ x,
                     const float* __restrict__ wq, const float* __restrict__ wk,
                     const float* __restrict__ wv,
                     uint16_t* __restrict__ x_bf, uint16_t* __restrict__ w_bf) {
    int i = blockIdx.x * blockDim.x + threadIdx.x;
    if (i < 2097152) {                           // x: 8388608 floats / 4
        const float4 v = ((const float4*)x)[i];
        ushort4 o;
        o.x = f2bf(v.x); o.y = f2bf(v.y); o.z = f2bf(v.z); o.w = f2bf(v.w);
        ((ushort4*)x_bf)[i] = o;
    } else {
        int e = (i - 2097152) * 4;               // w element, 3072x2048
        if (e >= 3072 * 2048) return;
        int row = e >> 11;
        int col = e & 2047;
        const float* src = (row < 2048) ? (wq + (long)row * 2048 + col)
                         : (row < 2560) ? (wk + (long)(row - 2048) * 2048 + col)
                                        : (wv + (long)(row - 2560) * 2048 + col);
        const float4 v = *(const float4*)src;
        ushort4 o;
        o.x = f2bf(v.x); o.y = f2bf(v.y); o.z = f2bf(v.z); o.w = f2bf(v.w);
        ((ushort4*)(w_bf + e))[0] = o;
    }
}

// ----------------------- pipelined 256-wide GEMM (NT) ------------------------
// C[m][n] = sum_k A[m][k]*B[n][k]. BM=256, BN in {192,128}, BK=64.
// 512 threads = 8 waves (2 M x 4 N). Double-buffered LDS; stage-ahead;
// ONE __syncthreads per K-tile; XOR swizzle both-sides; XCD-local col panels.
template <int BN, int OUT_BF16>
__global__ __launch_bounds__(512) void gemm256(const uint16_t* __restrict__ A,
                                               const uint16_t* __restrict__ Bw,
                                               void* __restrict__ Cout,
                                               int M, int N, int K) {
    constexpr int WN = BN / 4;        // per-wave cols
    constexpr int NF = WN / 16;       // B fragments per wave
    constexpr int BROUNDS = BN / 64;  // staging rounds for B

    __shared__ __align__(16) uint16_t As[2][256 * 64];
    __shared__ __align__(16) uint16_t Bs[2][BN * 64];

    const int n0 = blockIdx.x;                       // 0..255
    const int colt = 2 * (n0 & 7) + ((n0 >> 3) >> 4);
    const int rowt = (n0 >> 3) & 15;
    const long row0 = (long)rowt * 256;
    const long col0 = (long)colt * BN;

    const int tid = threadIdx.x;
    const int l = tid & 63;
    const int w = tid >> 6;
    const int wmi = w >> 2;           // 0..1
    const int wni = w & 3;            // 0..3
    const int c = l & 15, g = l >> 4;

    f32x4 acc[8][NF] = {};

    auto STAGE = [&](int buf, int t) {
        const long k0 = (long)t * 64;
#pragma unroll
        for (int rr = 0; rr < 4; ++rr) {
            const int e = rr * 512 + tid;            // 16B-slot index
            const int r = e >> 3;                    // row 0..255
            const int gs = (e & 7) ^ (r & 7);        // inverse-swizzled global slot
            async_cp16(A + (row0 + r) * (long)K + k0 + gs * 8, &As[buf][e * 8]);
        }
#pragma unroll
        for (int rr = 0; rr < BROUNDS; ++rr) {
            const int e = rr * 512 + tid;
            const int r = e >> 3;
            const int gs = (e & 7) ^ (r & 7);
            async_cp16(Bw + (col0 + r) * (long)K + k0 + gs * 8, &Bs[buf][e * 8]);
        }
    };

    STAGE(0, 0);
    __syncthreads();                                  // vmcnt(0) drain + barrier

    const int nt = K / 64;
    for (int t = 0; t < nt; ++t) {
        const int cur = t & 1;
        if (t + 1 < nt) STAGE(cur ^ 1, t + 1);        // overlaps this tile's compute

#pragma unroll
        for (int kk = 0; kk < 2; ++kk) {
            bf16x8 bF[NF];
#pragma unroll
            for (int n = 0; n < NF; ++n) {
                const int rb = wni * WN + n * 16 + c;
                const int sp = ((kk * 4 + g) ^ (c & 7));
                bF[n] = *(const bf16x8*)&Bs[cur][rb * 64 + sp * 8];
            }
#pragma unroll
            for (int mh = 0; mh < 2; ++mh) {
                bf16x8 aF[4];
#pragma unroll
                for (int mm = 0; mm < 4; ++mm) {
                    const int ra = wmi * 128 + (mh * 4 + mm) * 16 + c;
                    const int sp = ((kk * 4 + g) ^ (c & 7));
                    aF[mm] = *(const bf16x8*)&As[cur][ra * 64 + sp * 8];
                }
                __builtin_amdgcn_s_setprio(1);
#pragma unroll
                for (int mm = 0; mm < 4; ++mm)
#pragma unroll
                    for (int n = 0; n < NF; ++n)
                        acc[mh * 4 + mm][n] = __builtin_amdgcn_mfma_f32_16x16x32_bf16(
                            aF[mm], bF[n], acc[mh * 4 + mm][n], 0, 0, 0);
                __builtin_amdgcn_s_setprio(0);
            }
        }
        if (t + 1 < nt) __syncthreads();              // next buffer staged; cur reads done
    }

#pragma unroll
    for (int m = 0; m < 8; ++m) {
        const long rg = row0 + wmi * 128 + m * 16 + g * 4;
#pragma unroll
        for (int n = 0; n < NF; ++n) {
            const long cg = col0 + wni * WN + n * 16 + c;
#pragma unroll
            for (int r = 0; r < 4; ++r) {
                float v = acc[m][n][r];
                if (OUT_BF16)
                    ((uint16_t*)Cout)[(rg + r) * (long)N + cg] = f2bf(v);
                else
                    ((float*)Cout)[(rg + r) * (long)N + cg] = v;
            }
        }
    }
}

// ---------- K (fused RoPE) + V^T -> fragment-order pack, one kernel ----------
// Kpk[bk][tile(64)][s(4)][lane(64)][8], Vpk[bk][tile(64)][nd(2)][s2(2)][lane][8]
__global__ void pack_kv(const uint16_t* __restrict__ qkv,
                        const float* __restrict__ cosT,
                        const float* __restrict__ sinT,
                        uint16_t* __restrict__ Kpk,
                        uint16_t* __restrict__ Vpk) {
    const int gw = (blockIdx.x * blockDim.x + threadIdx.x) >> 6;  // 8192 waves
    const int l = threadIdx.x & 63;
    const int lq = l & 31, hi = l >> 5;
    if (gw < 4096) {
        const int wid = gw;
        const int s = wid & 3;
        const int tile = (wid >> 2) & 63;
        const int bk = wid >> 8;
        const int b = bk >> 3, kvh = bk & 7;
        const int key = 32 * tile + lq;
        const uint16_t* src = qkv + (long)(b * 2048 + key) * 3072
                            + 2048 + kvh * 64 + 16 * s + 8 * hi;
        u16x8 v = *(const u16x8*)src;
        const int d2b = 8 * s + 4 * hi;            // first pair index
        u16x8 o;
#pragma unroll
        for (int p = 0; p < 4; ++p) {
            const float cc = cosT[key * 32 + d2b + p];
            const float ss = sinT[key * 32 + d2b + p];
            const float re = bf2f(v[2 * p]);
            const float im = bf2f(v[2 * p + 1]);
            o[2 * p]     = f2bf(re * cc - im * ss);
            o[2 * p + 1] = f2bf(re * ss + im * cc);
        }
        *(u16x8*)(Kpk + (((long)(bk * 64 + tile) * 4 + s) * 64 + l) * 8) = o;
    } else {
        const int wid = gw - 4096;
        const int s2 = wid & 1;
        const int nd = (wid >> 1) & 1;
        const int tile = (wid >> 2) & 63;
        const int bk = wid >> 8;
        const int b = bk >> 3, kvh = bk & 7;
        const int key0 = 32 * tile + 16 * s2 + 8 * hi;
        const uint16_t* src = qkv + (long)(b * 2048 + key0) * 3072
                            + 2560 + kvh * 64 + nd * 32 + lq;
        u16x8 v;
#pragma unroll
        for (int jj = 0; jj < 8; ++jj) v[jj] = src[(long)jj * 3072];
        *(u16x8*)(Vpk + ((((long)(bk * 64 + tile) * 2 + nd) * 2 + s2) * 64 + l) * 8) = v;
    }
}

// ---------- P^T fragment assembly via permlane32_swap (verified R10+) --------
__device__ inline void pack_pf(const float pr[16], bf16x8 pf[2]) {
    uint32_t wds[8];
#pragma unroll
    for (int m = 0; m < 8; ++m)
        wds[m] = (uint32_t)f2bf(pr[2 * m]) | ((uint32_t)f2bf(pr[2 * m + 1]) << 16);
    asm volatile("v_permlane32_swap_b32 %0, %1" : "+v"(wds[0]), "+v"(wds[2]));
    asm volatile("v_permlane32_swap_b32 %0, %1" : "+v"(wds[1]), "+v"(wds[3]));
    asm volatile("v_permlane32_swap_b32 %0, %1" : "+v"(wds[4]), "+v"(wds[6]));
    asm volatile("v_permlane32_swap_b32 %0, %1" : "+v"(wds[5]), "+v"(wds[7]));
    u32x4 pk0 = {wds[0], wds[1], wds[2], wds[3]};
    u32x4 pk1 = {wds[4], wds[5], wds[6], wds[7]};
    pf[0] = __builtin_bit_cast(bf16x8, pk0);
    pf[1] = __builtin_bit_cast(bf16x8, pk1);
}

// ---------------------------- flash attention (R12) --------------------------
// 2048 blocks x 128 threads (2 waves). Block = (rowset j, head-pair); j
// dispatched descending (LPT). Per lane-pair (l,l+32) one q-row in-register:
// Q loaded RAW and RoPE+scale applied in the prologue; swapped QK^T
// (S^T = mfma(K,Q), log2 domain), in-register online softmax (tree max/sum,
// defer-max T13), P^T via permlane32_swap, PV: O^T = mfma(V^T, P^T).
__global__ __launch_bounds__(128) void attn_fwd(const uint16_t* __restrict__ qkv,
                                                const float* __restrict__ cosT,
                                                const float* __restrict__ sinT,
                                                const uint16_t* __restrict__ Kpk,
                                                const uint16_t* __restrict__ Vpk,
                                                uint16_t* __restrict__ outb) {
    const int bid = blockIdx.x;
    const int bhp = bid & 31;
    const int j = 63 - (bid >> 5);              // rowset index, longest first
    const int t0 = threadIdx.x;
    const int l = t0 & 63, ww = t0 >> 6;
    const int gh = 2 * bhp + ww;                // global head 0..63
    const int b = gh >> 5, h = gh & 31;
    const int kvh = h >> 2;
    const int bk = b * 8 + kvh;
    const int lq = l & 31, hi = l >> 5;
    const int q = 32 * j + lq;

    // Q B-fragments: load raw Q[q][d = 16s+8hi+jj], apply RoPE + SCALE_LOG2.
    const uint16_t* qrow = qkv + (long)(b * 2048 + q) * 3072 + h * 64 + 8 * hi;
    bf16x8 qf[4];
#pragma unroll
    for (int s = 0; s < 4; ++s) {
        const u16x8 v = *(const u16x8*)(qrow + 16 * s);
        const int d2b = 8 * s + 4 * hi;
        u16x8 o;
#pragma unroll
        for (int p = 0; p < 4; ++p) {
            const float cc = cosT[q * 32 + d2b + p];
            const float ss = sinT[q * 32 + d2b + p];
            const float re = bf2f(v[2 * p]);
            const float im = bf2f(v[2 * p + 1]);
            o[2 * p]     = f2bf((re * cc - im * ss) * SCALE_LOG2);
            o[2 * p + 1] = f2bf((re * ss + im * cc) * SCALE_LOG2);
        }
        qf[s] = __builtin_bit_cast(bf16x8, o);
    }

    float m_run = -1e30f, l_run = 0.f;
    f32x16 accO[2] = {};                         // O^T[d = nd*32 + roff][q]

    const uint16_t* kbase = Kpk + (long)bk * 64 * 2048 + (long)l * 8;
    const uint16_t* vbase = Vpk + (long)bk * 64 * 2048 + (long)l * 8;
    const int nT = (j + 2) >> 1;                 // 64-key iterations

    for (int t = 0; t < nT; ++t) {
        // ---- K A-fragments for both 32-key subtiles (coalesced) ----
        bf16x8 kf[2][4];
#pragma unroll
        for (int u = 0; u < 2; ++u)
#pragma unroll
            for (int s = 0; s < 4; ++s)
                kf[u][s] = *(const bf16x8*)(kbase + (long)(2 * t + u) * 2048 + s * 512);

        // ---- S^T = K Q^T (pre-scaled, log2 domain) ----
        f32x16 st0 = {}, st1 = {};
        __builtin_amdgcn_s_setprio(1);
#pragma unroll
        for (int s = 0; s < 4; ++s)
            st0 = __builtin_amdgcn_mfma_f32_32x32x16_bf16(kf[0][s], qf[s], st0, 0, 0, 0);
#pragma unroll
        for (int s = 0; s < 4; ++s)
            st1 = __builtin_amdgcn_mfma_f32_32x32x16_bf16(kf[1][s], qf[s], st1, 0, 0, 0);
        __builtin_amdgcn_s_setprio(0);

        // ---- V^T A-fragments (kf dead; softmax below hides latency) ----
        bf16x8 vf[2][2][2];
#pragma unroll
        for (int u = 0; u < 2; ++u)
#pragma unroll
            for (int nd = 0; nd < 2; ++nd)
#pragma unroll
                for (int s2 = 0; s2 < 2; ++s2)
                    vf[u][nd][s2] = *(const bf16x8*)(vbase + (long)(2 * t + u) * 2048 + nd * 1024 + s2 * 512);

        // ---- causal mask in-place (last iteration only) ----
        if (t == nT - 1) {
            const int tq0 = lq + ((j - 2 * t) << 5) - 4 * hi;
            const int tq1 = tq0 - 32;
#pragma unroll
            for (int r = 0; r < 16; ++r) {
                const int kc = (r & 3) + 8 * (r >> 2);
                if (kc > tq0) st0[r] = NEG_BIG;
                if (kc > tq1) st1[r] = NEG_BIG;
            }
        }

        // ---- 64-key max (binary tree) ----
        float mx[16];
#pragma unroll
        for (int r = 0; r < 16; ++r) mx[r] = fmaxf(st0[r], st1[r]);
#pragma unroll
        for (int off = 8; off; off >>= 1)
#pragma unroll
            for (int r = 0; r < 8; ++r)
                if (r < off) mx[r] = fmaxf(mx[r], mx[r + off]);
        const float vm = fmaxf(mx[0], __shfl_xor(mx[0], 32));

        // ---- defer-max rescale (T13) ----
        if (!__all(vm - m_run <= DEFER_THR)) {
            const float mnew = fmaxf(m_run, vm);
            const float alpha = __builtin_amdgcn_exp2f(m_run - mnew);
            m_run = mnew;
            l_run *= alpha;
#pragma unroll
            for (int nd = 0; nd < 2; ++nd)
#pragma unroll
                for (int r = 0; r < 16; ++r) accO[nd][r] *= alpha;
        }

        // ---- exp + row-sum (tree) ----
        float pr0[16], pr1[16], sm[8];
#pragma unroll
        for (int r = 0; r < 16; ++r) pr0[r] = __builtin_amdgcn_exp2f(st0[r] - m_run);
#pragma unroll
        for (int r = 0; r < 16; ++r) pr1[r] = __builtin_amdgcn_exp2f(st1[r] - m_run);
#pragma unroll
        for (int m = 0; m < 8; ++m)
            sm[m] = (pr0[2 * m] + pr0[2 * m + 1]) + (pr1[2 * m] + pr1[2 * m + 1]);
#pragma unroll
        for (int off = 4; off; off >>= 1)
#pragma unroll
            for (int r = 0; r < 4; ++r)
                if (r < off) sm[r] += sm[r + off];
        l_run += sm[0] + __shfl_xor(sm[0], 32);

        // ---- P^T fragments (permlane32_swap), PV accumulate ----
        bf16x8 pf0[2], pf1[2];
        pack_pf(pr0, pf0);
        pack_pf(pr1, pf1);

        __builtin_amdgcn_s_setprio(1);
#pragma unroll
        for (int nd = 0; nd < 2; ++nd) {
            accO[nd] = __builtin_amdgcn_mfma_f32_32x32x16_bf16(vf[0][nd][0], pf0[0], accO[nd], 0, 0, 0);
            accO[nd] = __builtin_amdgcn_mfma_f32_32x32x16_bf16(vf[0][nd][1], pf0[1], accO[nd], 0, 0, 0);
            accO[nd] = __builtin_amdgcn_mfma_f32_32x32x16_bf16(vf[1][nd][0], pf1[0], accO[nd], 0, 0, 0);
            accO[nd] = __builtin_amdgcn_mfma_f32_32x32x16_bf16(vf[1][nd][1], pf1[1], accO[nd], 0, 0, 0);
        }
        __builtin_amdgcn_s_setprio(0);
    }

    // ---- epilogue: out[b, q, h*64 + d], d = nd*32 + (r&3)+4hi+8(r>>2) ----
    const float invl = 1.0f / l_run;
    uint16_t* orow = outb + (long)(b * 2048 + q) * 2048 + h * 64 + 4 * hi;
#pragma unroll
    for (int nd = 0; nd < 2; ++nd)
#pragma unroll
        for (int m = 0; m < 4; ++m) {
            ushort4 o;
            o.x = f2bf(accO[nd][4 * m + 0] * invl);
            o.y = f2bf(accO[nd][4 * m + 1] * invl);
            o.z = f2bf(accO[nd][4 * m + 2] * invl);
            o.w = f2bf(accO[nd][4 * m + 3] * invl);
            *(ushort4*)(orow + nd * 32 + 8 * m) = o;
        }
}

// ---------------------------------------------------------------------------
extern "C" void kernel_launch(void* const* d_in, const int* in_sizes, int n_in,
                              void* d_out, int out_size, void* d_ws, size_t ws_size,
                              hipStream_t stream) {
    const float* x    = (const float*)d_in[0];
    const float* wq   = (const float*)d_in[1];
    const float* wk   = (const float*)d_in[2];
    const float* wv   = (const float*)d_in[3];
    const float* wo   = (const float*)d_in[4];
    const float* fcos = (const float*)d_in[5];
    const float* fsin = (const float*)d_in[6];
    // d_in[7] = mask: causal, computed analytically in attn_fwd.
    float* out = (float*)d_out;

    uint8_t* ws = (uint8_t*)d_ws;
    // layout (bytes), total 52 MiB:
    //   [0,        16 MiB)   x_bf [4096][2048]   -- reused as att_bf
    //   [16 MiB,   28 MiB)   w_bf [3072][2048]   -- after GEMM1:
    //                          Kpk @16MiB (4MiB), Vpk @20MiB (4MiB);
    //                          after attn: wo_bf @16MiB (8MiB)
    //   [28 MiB,   52 MiB)   qkv_bf [4096][3072]
    const size_t MiB = 1048576;
    uint16_t* x_bf   = (uint16_t*)(ws);
    uint16_t* w_bf   = (uint16_t*)(ws + 16 * MiB);
    uint16_t* qkv_bf = (uint16_t*)(ws + 28 * MiB);
    uint16_t* att_bf = x_bf;                        // alias after GEMM1
    uint16_t* Kpk    = (uint16_t*)(ws + 16 * MiB);  // alias after GEMM1
    uint16_t* Vpk    = (uint16_t*)(ws + 20 * MiB);
    uint16_t* wo_bf  = (uint16_t*)(ws + 16 * MiB);  // alias after attn

    // 1) fused casts: x -> x_bf, [wq;wk;wv] -> w_bf (one launch)
    prep<<<(2097152 + 1572864 + 255) / 256, 256, 0, stream>>>(x, wq, wk, wv, x_bf, w_bf);

    // 2) QKV projection: [4096][3072] = x_bf @ w_bf^T  (256x192, 256 blocks,
    //    XCD-local column panels)
    gemm256<192, 1><<<256, 512, 0, stream>>>(x_bf, w_bf, qkv_bf, 4096, 3072, 2048);

    // 3) K-RoPE + fragment packs (Q stays raw; attn ropes Q in-register)
    pack_kv<<<2048, 256, 0, stream>>>(qkv_bf, fcos, fsin, Kpk, Vpk);

    // 4) flash attention -> att_bf [4096][2048]
    attn_fwd<<<2048, 128, 0, stream>>>(qkv_bf, fcos, fsin, Kpk, Vpk, att_bf);

    // 5) wo cast (Kpk/Vpk dead now), O projection -> fp32 out (256x128,
    //    256 blocks, XCD-local column panels)
    cvt4<<<(1048576 + 255) / 256, 256, 0, stream>>>(wo, wo_bf, 1048576);
    gemm256<128, 0><<<256, 512, 0, stream>>>(att_bf, wo_bf, out, 4096, 2048, 2048);
}